// Round 1
// baseline (180.732 us; speedup 1.0000x reference)
//
#include <hip/hip_runtime.h>

// B=16, Lk=2048, Lq=256, DIM=512, HEADS=8, d_k=64 — f32 I/O, bf16 MFMA internally.
// out = softmax((G@Wq+bq) heads @ L^T * scale) @ L, merge heads, @ Wo + bo
#define KSTR 72   // attn P-buffer row stride (shorts)

typedef __attribute__((ext_vector_type(8))) short short8;  // 8 bf16 (4 VGPRs)
typedef __attribute__((ext_vector_type(4))) float f32x4;

#define EXP2F(x) __builtin_amdgcn_exp2f(x)

__device__ __forceinline__ unsigned short f2bf(float f) {   // RNE f32->bf16
    union { float f; unsigned u; } v; v.f = f;
    unsigned r = v.u + 0x7fff + ((v.u >> 16) & 1);
    return (unsigned short)(r >> 16);
}
__device__ __forceinline__ unsigned pk2(float a, float b) {
    return (unsigned)f2bf(a) | ((unsigned)f2bf(b) << 16);
}

// ---- W[512,512] f32 -> WF frag-order bf16: WF[kt][ntg][lane][8] with
// elem j = W[32kt+8quad+j][16ntg+c], lane=(quad<<4)|c. blockIdx.y picks matrix.
__global__ __launch_bounds__(256) void conv_W(const float* __restrict__ Wq,
                                              const float* __restrict__ Wo,
                                              unsigned short* __restrict__ WqF,
                                              unsigned short* __restrict__ WoF) {
    const float* W = blockIdx.y ? Wo : Wq;
    unsigned short* WF = blockIdx.y ? WoF : WqF;
    int g = blockIdx.x * 256 + threadIdx.x;       // [0, 32768)
    int lane = g & 63, ntg = (g >> 6) & 31, kt = g >> 11;
    int c = lane & 15, quad = lane >> 4;
    const float* wp = W + (size_t)(32 * kt + 8 * quad) * 512 + 16 * ntg + c;
    float v[8];
    #pragma unroll
    for (int j = 0; j < 8; j++) v[j] = wp[(size_t)j * 512];
    uint4 u;
    u.x = pk2(v[0], v[1]); u.y = pk2(v[2], v[3]);
    u.z = pk2(v[4], v[5]); u.w = pk2(v[6], v[7]);
    *(uint4*)(WF + (size_t)g * 8) = u;
}

// ---- L[16,2048,512] f32 -> KF + VF frag tensors (bf16), per (b,h,t) 64x64 tile.
__global__ __launch_bounds__(256) void conv_L(const float* __restrict__ Lmat,
                                              unsigned short* __restrict__ KF,
                                              unsigned short* __restrict__ VF) {
    __shared__ unsigned short KFs[4096];
    __shared__ unsigned short VFs[4096];
    const int blk = blockIdx.x;            // ((b*8+h)*32+t)
    const int t = blk & 31, h = (blk >> 5) & 7, b = blk >> 8;
    const int tid = threadIdx.x;
    const int key = tid & 63, wv = tid >> 6;   // 16 d's per thread

    const float* src = Lmat + ((size_t)(b * 2048 + 64 * t + key)) * 512 + 64 * h + 16 * wv;
    float4 a0 = *(const float4*)src;
    float4 a1 = *(const float4*)(src + 4);
    float4 a2 = *(const float4*)(src + 8);
    float4 a3 = *(const float4*)(src + 12);
    float vals[16] = {a0.x, a0.y, a0.z, a0.w, a1.x, a1.y, a1.z, a1.w,
                      a2.x, a2.y, a2.z, a2.w, a3.x, a3.y, a3.z, a3.w};
    #pragma unroll
    for (int i = 0; i < 16; i++) {
        int d = 16 * wv + i;
        unsigned short bv = f2bf(vals[i]);
        KFs[((((key >> 4) * 2 + (d >> 5)) * 64) + ((d >> 3) & 3) * 16 + (key & 15)) * 8 + (d & 7)] = bv;
        VFs[((((d >> 4) * 2 + (key >> 5)) * 64) + ((key >> 3) & 3) * 16 + (d & 15)) * 8 + (key & 7)] = bv;
    }
    __syncthreads();
    size_t gbase = (size_t)blk * 4096 + tid * 16;
    *(uint4*)(KF + gbase)     = *(const uint4*)&KFs[tid * 16];
    *(uint4*)(KF + gbase + 8) = *(const uint4*)&KFs[tid * 16 + 8];
    *(uint4*)(VF + gbase)     = *(const uint4*)&VFs[tid * 16];
    *(uint4*)(VF + gbase + 8) = *(const uint4*)&VFs[tid * 16 + 8];
}

// ---- barrier-free gemm: C[M,512] = (A@W + bias)*oscale. No LDS, no syncs.
// Wave wv owns rows m0+16wv..+15, cols n0..+63. A-frags loaded DIRECTLY from
// global (lane (c,quad): row m0+16wv+c, k=32kk+8quad..+7 — contiguous 32B),
// B-frags from pre-fragged WF (L2-resident). Full K unroll -> pipelined loads.
// launch_bounds(256,2): grid is 512 blocks = 2 blocks/CU (grid-limited), so
// VGPR up to 256 is free — let the compiler keep the unrolled loads hoisted.
template<bool A_BF16, bool OUT_BF16>
__global__ __launch_bounds__(256, 2) void gemm_direct(const void* __restrict__ Ap,
                                                      const unsigned short* __restrict__ WF,
                                                      const float* __restrict__ bias,
                                                      void* __restrict__ Cp,
                                                      float oscale) {
    const int tid = threadIdx.x;
    const int wv = tid >> 6, lane = tid & 63;
    const int c = lane & 15, quad = lane >> 4;
    const int m0 = blockIdx.x * 64, n0 = blockIdx.y * 64;
    const int row = m0 + 16 * wv + c;

    f32x4 acc[4];
    #pragma unroll
    for (int nt = 0; nt < 4; nt++) acc[nt] = (f32x4){0.f, 0.f, 0.f, 0.f};

    #pragma unroll
    for (int kk = 0; kk < 16; kk++) {
        short8 af;
        if (A_BF16) {
            af = *(const short8*)((const unsigned short*)Ap + (size_t)row * 512 + 32 * kk + 8 * quad);
        } else {
            const float* ap = (const float*)Ap + (size_t)row * 512 + 32 * kk + 8 * quad;
            float4 x0 = *(const float4*)ap;
            float4 x1 = *(const float4*)(ap + 4);
            af[0] = (short)f2bf(x0.x); af[1] = (short)f2bf(x0.y);
            af[2] = (short)f2bf(x0.z); af[3] = (short)f2bf(x0.w);
            af[4] = (short)f2bf(x1.x); af[5] = (short)f2bf(x1.y);
            af[6] = (short)f2bf(x1.z); af[7] = (short)f2bf(x1.w);
        }
        #pragma unroll
        for (int nt = 0; nt < 4; nt++) {
            short8 bf = *(const short8*)(WF +
                (((size_t)kk * 32 + (n0 >> 4) + nt) * 64 + lane) * 8);
            acc[nt] = __builtin_amdgcn_mfma_f32_16x16x32_bf16(af, bf, acc[nt], 0, 0, 0);
        }
    }

    #pragma unroll
    for (int nt = 0; nt < 4; nt++) {
        float bv = bias[n0 + 16 * nt + c];
        #pragma unroll
        for (int r = 0; r < 4; r++) {
            float v = (acc[nt][r] + bv) * oscale;
            size_t idx = (size_t)(m0 + 16 * wv + 4 * quad + r) * 512 + n0 + 16 * nt + c;
            if (OUT_BF16) ((unsigned short*)Cp)[idx] = f2bf(v);
            else          ((float*)Cp)[idx] = v;
        }
    }
}

// ---- barrier-free MFMA flash attention, XCD-swizzled grid: the 4 qt-blocks
// of one (b,h) share blockIdx%8 -> same XCD -> shared L2 stream of KF/VF.
// No-max softmax (Q pre-scaled by scale*log2e); row sums via ones-MFMA.
// launch_bounds(256,2): grid = 512 blocks = 2 blocks/CU (grid-limited), so the
// K/V register double-buffer (~190 live VGPRs) is free; without this the
// compiler capped at 100 VGPRs and sank the prefetch loads next to their uses,
// exposing full L2 latency every tile (measured: MfmaUtil 16.5%, ~1575 cy/tile
// vs ~340 cy issue cost).
__global__ __launch_bounds__(256, 2) void attn_frag(const unsigned short* __restrict__ Q,
                                                    const unsigned short* __restrict__ KF,
                                                    const unsigned short* __restrict__ VF,
                                                    unsigned short* __restrict__ X) {
    __shared__ unsigned short Pw[4][16 * KSTR];

    // swizzle: raw = xcd + 8*(qt + 4*grp); bh = grp*8 + xcd -> b=grp, h=xcd
    const int raw = blockIdx.x;
    const int h  = raw & 7;            // = xcd slot
    const int qt = (raw >> 3) & 3;
    const int b  = raw >> 5;
    const int tid = threadIdx.x;
    const int wv = tid >> 6, lane = tid & 63;
    const int c = lane & 15, quad = lane >> 4;

    short8 qa[2];
    {
        const unsigned short* qsrc =
            Q + ((size_t)(b * 256 + qt * 64 + 16 * wv + c)) * 512 + h * 64;
        qa[0] = *(const short8*)(qsrc + 8 * quad);
        qa[1] = *(const short8*)(qsrc + 32 + 8 * quad);
    }
    short8 ones;
    #pragma unroll
    for (int i = 0; i < 8; i++) ones[i] = (short)0x3F80;

    f32x4 oacc[4];
    #pragma unroll
    for (int dt = 0; dt < 4; dt++) oacc[dt] = (f32x4){0.f, 0.f, 0.f, 0.f};
    f32x4 lacc = (f32x4){0.f, 0.f, 0.f, 0.f};

    const int swc = (c >> 3) & 1;
    const int swr = (quad >> 1) & 1;

    const unsigned short* kf = KF + ((size_t)((b * 8 + h) * 32)) * 4096 + lane * 8;
    const unsigned short* vf = VF + ((size_t)((b * 8 + h) * 32)) * 4096 + lane * 8;

    short8 kc[8], vc[8], kn[8], vn[8];
    #pragma unroll
    for (int f = 0; f < 8; f++) {
        kc[f] = *(const short8*)(kf + f * 512);
        vc[f] = *(const short8*)(vf + f * 512);
    }

    auto compute = [&](short8* kb, short8* vb) {
        f32x4 sacc[4];
        #pragma unroll
        for (int nt = 0; nt < 4; nt++) sacc[nt] = (f32x4){0.f, 0.f, 0.f, 0.f};
        #pragma unroll
        for (int nt = 0; nt < 4; nt++)
            #pragma unroll
            for (int ks = 0; ks < 2; ks++)
                sacc[nt] = __builtin_amdgcn_mfma_f32_16x16x32_bf16(
                    qa[ks], kb[nt * 2 + ks], sacc[nt], 0, 0, 0);
        #pragma unroll
        for (int nt = 0; nt < 4; nt++)
            #pragma unroll
            for (int r = 0; r < 4; r++)
                Pw[wv][(4 * quad + r) * KSTR + ((16 * nt + c) ^ (8 * swr))] =
                    f2bf(EXP2F(sacc[nt][r]));
        short8 pa0 = *(const short8*)&Pw[wv][c * KSTR + (8 * (quad ^ swc))];
        short8 pa1 = *(const short8*)&Pw[wv][c * KSTR + 32 + (8 * (quad ^ swc))];
        #pragma unroll
        for (int dt = 0; dt < 4; dt++) {
            oacc[dt] = __builtin_amdgcn_mfma_f32_16x16x32_bf16(pa0, vb[dt * 2], oacc[dt], 0, 0, 0);
            oacc[dt] = __builtin_amdgcn_mfma_f32_16x16x32_bf16(pa1, vb[dt * 2 + 1], oacc[dt], 0, 0, 0);
        }
        lacc = __builtin_amdgcn_mfma_f32_16x16x32_bf16(pa0, ones, lacc, 0, 0, 0);
        lacc = __builtin_amdgcn_mfma_f32_16x16x32_bf16(pa1, ones, lacc, 0, 0, 0);
    };

    for (int t = 0; t < 32; t += 2) {
        {   // load tile t+1
            const unsigned short* k2 = kf + (size_t)(t + 1) * 4096;
            const unsigned short* v2 = vf + (size_t)(t + 1) * 4096;
            #pragma unroll
            for (int f = 0; f < 8; f++) {
                kn[f] = *(const short8*)(k2 + f * 512);
                vn[f] = *(const short8*)(v2 + f * 512);
            }
        }
        compute(kc, vc);
        if (t + 2 < 32) {   // load tile t+2 while computing t+1
            const unsigned short* k2 = kf + (size_t)(t + 2) * 4096;
            const unsigned short* v2 = vf + (size_t)(t + 2) * 4096;
            #pragma unroll
            for (int f = 0; f < 8; f++) {
                kc[f] = *(const short8*)(k2 + f * 512);
                vc[f] = *(const short8*)(v2 + f * 512);
            }
        }
        compute(kn, vn);
    }

    #pragma unroll
    for (int r = 0; r < 4; r++) {
        float inv = 1.f / lacc[r];
        size_t row = (size_t)(b * 256 + qt * 64 + 16 * wv + 4 * quad + r);
        unsigned short* xp = X + row * 512 + h * 64;
        #pragma unroll
        for (int dt = 0; dt < 4; dt++)
            xp[16 * dt + c] = f2bf(oacc[dt][r] * inv);
    }
}

// ---------------------------------------------------------------------------
extern "C" void kernel_launch(void* const* d_in, const int* in_sizes, int n_in,
                              void* d_out, int out_size, void* d_ws, size_t ws_size,
                              hipStream_t stream) {
    const float* Lmat = (const float*)d_in[0];  // [16,2048,512]
    const float* G    = (const float*)d_in[1];  // [16,256,512]
    const float* Wq   = (const float*)d_in[2];  // [512,512]
    const float* bq   = (const float*)d_in[3];  // [512]
    const float* Wo   = (const float*)d_in[4];  // [512,512]
    const float* bo   = (const float*)d_in[5];  // [512]
    float* out = (float*)d_out;                 // [16,256,512] f32

    const float SCe = 0.005524271728019903f * 1.4426950408889634f;  // scale*log2e
    dim3 gg(64, 8);

    // ws layout (bf16 elems): Qws 2M | Xws 2M | WqF 256K | WoF 256K | KF 16M | VF 16M
    // (ws_size >= 76.5 MB verified on-device in round 7: frag path ran)
    unsigned short* Qws = (unsigned short*)d_ws;
    unsigned short* Xws = Qws + (size_t)2097152;
    unsigned short* WqF = Xws + (size_t)2097152;
    unsigned short* WoF = WqF + (size_t)262144;
    unsigned short* KF  = WoF + (size_t)262144;
    unsigned short* VF  = KF  + (size_t)16777216;

    conv_W<<<dim3(128, 2), 256, 0, stream>>>(Wq, Wo, WqF, WoF);
    conv_L<<<4096, 256, 0, stream>>>(Lmat, KF, VF);
    gemm_direct<false, true><<<gg, 256, 0, stream>>>(G, WqF, bq, Qws, SCe);
    attn_frag<<<512, 256, 0, stream>>>(Qws, KF, VF, Xws);
    gemm_direct<true, false><<<gg, 256, 0, stream>>>(Xws, WoF, bo, out, 1.0f);
}

// Round 2
// 179.917 us; speedup vs baseline: 1.0045x; 1.0045x over previous
//
#include <hip/hip_runtime.h>

// B=16, Lk=2048, Lq=256, DIM=512, HEADS=8, d_k=64 — f32 I/O, bf16 MFMA internally.
// out = softmax((G@Wq+bq) heads @ L^T * scale) @ L, merge heads, @ Wo + bo
#define KSTR 72   // attn P-buffer row stride (shorts)

typedef __attribute__((ext_vector_type(8))) short short8;  // 8 bf16 (4 VGPRs)
typedef __attribute__((ext_vector_type(4))) float f32x4;

#define EXP2F(x) __builtin_amdgcn_exp2f(x)

__device__ __forceinline__ unsigned short f2bf(float f) {   // RNE f32->bf16
    union { float f; unsigned u; } v; v.f = f;
    unsigned r = v.u + 0x7fff + ((v.u >> 16) & 1);
    return (unsigned short)(r >> 16);
}
__device__ __forceinline__ unsigned pk2(float a, float b) {
    return (unsigned)f2bf(a) | ((unsigned)f2bf(b) << 16);
}

// ---- W[512,512] f32 -> WF frag-order bf16: WF[kt][ntg][lane][8] with
// elem j = W[32kt+8quad+j][16ntg+c], lane=(quad<<4)|c. blockIdx.y picks matrix.
__global__ __launch_bounds__(256) void conv_W(const float* __restrict__ Wq,
                                              const float* __restrict__ Wo,
                                              unsigned short* __restrict__ WqF,
                                              unsigned short* __restrict__ WoF) {
    const float* W = blockIdx.y ? Wo : Wq;
    unsigned short* WF = blockIdx.y ? WoF : WqF;
    int g = blockIdx.x * 256 + threadIdx.x;       // [0, 32768)
    int lane = g & 63, ntg = (g >> 6) & 31, kt = g >> 11;
    int c = lane & 15, quad = lane >> 4;
    const float* wp = W + (size_t)(32 * kt + 8 * quad) * 512 + 16 * ntg + c;
    float v[8];
    #pragma unroll
    for (int j = 0; j < 8; j++) v[j] = wp[(size_t)j * 512];
    uint4 u;
    u.x = pk2(v[0], v[1]); u.y = pk2(v[2], v[3]);
    u.z = pk2(v[4], v[5]); u.w = pk2(v[6], v[7]);
    *(uint4*)(WF + (size_t)g * 8) = u;
}

// ---- L[16,2048,512] f32 -> KF + VF frag tensors (bf16), per (b,h,t) 64x64 tile.
__global__ __launch_bounds__(256) void conv_L(const float* __restrict__ Lmat,
                                              unsigned short* __restrict__ KF,
                                              unsigned short* __restrict__ VF) {
    __shared__ unsigned short KFs[4096];
    __shared__ unsigned short VFs[4096];
    const int blk = blockIdx.x;            // ((b*8+h)*32+t)
    const int t = blk & 31, h = (blk >> 5) & 7, b = blk >> 8;
    const int tid = threadIdx.x;
    const int key = tid & 63, wv = tid >> 6;   // 16 d's per thread

    const float* src = Lmat + ((size_t)(b * 2048 + 64 * t + key)) * 512 + 64 * h + 16 * wv;
    float4 a0 = *(const float4*)src;
    float4 a1 = *(const float4*)(src + 4);
    float4 a2 = *(const float4*)(src + 8);
    float4 a3 = *(const float4*)(src + 12);
    float vals[16] = {a0.x, a0.y, a0.z, a0.w, a1.x, a1.y, a1.z, a1.w,
                      a2.x, a2.y, a2.z, a2.w, a3.x, a3.y, a3.z, a3.w};
    #pragma unroll
    for (int i = 0; i < 16; i++) {
        int d = 16 * wv + i;
        unsigned short bv = f2bf(vals[i]);
        KFs[((((key >> 4) * 2 + (d >> 5)) * 64) + ((d >> 3) & 3) * 16 + (key & 15)) * 8 + (d & 7)] = bv;
        VFs[((((d >> 4) * 2 + (key >> 5)) * 64) + ((key >> 3) & 3) * 16 + (d & 15)) * 8 + (key & 7)] = bv;
    }
    __syncthreads();
    size_t gbase = (size_t)blk * 4096 + tid * 16;
    *(uint4*)(KF + gbase)     = *(const uint4*)&KFs[tid * 16];
    *(uint4*)(KF + gbase + 8) = *(const uint4*)&KFs[tid * 16 + 8];
    *(uint4*)(VF + gbase)     = *(const uint4*)&VFs[tid * 16];
    *(uint4*)(VF + gbase + 8) = *(const uint4*)&VFs[tid * 16 + 8];
}

// ---- barrier-free gemm: C[M,512] = (A@W + bias)*oscale. No LDS, no syncs.
// Wave wv owns rows m0+16wv..+15, cols n0..+63. A-frags loaded DIRECTLY from
// global (lane (c,quad): row m0+16wv+c, k=32kk+8quad..+7 — contiguous 32B),
// B-frags from pre-fragged WF (L2-resident). Full K unroll -> pipelined loads.
template<bool A_BF16, bool OUT_BF16>
__global__ __launch_bounds__(256, 2) void gemm_direct(const void* __restrict__ Ap,
                                                      const unsigned short* __restrict__ WF,
                                                      const float* __restrict__ bias,
                                                      void* __restrict__ Cp,
                                                      float oscale) {
    const int tid = threadIdx.x;
    const int wv = tid >> 6, lane = tid & 63;
    const int c = lane & 15, quad = lane >> 4;
    const int m0 = blockIdx.x * 64, n0 = blockIdx.y * 64;
    const int row = m0 + 16 * wv + c;

    f32x4 acc[4];
    #pragma unroll
    for (int nt = 0; nt < 4; nt++) acc[nt] = (f32x4){0.f, 0.f, 0.f, 0.f};

    #pragma unroll
    for (int kk = 0; kk < 16; kk++) {
        short8 af;
        if (A_BF16) {
            af = *(const short8*)((const unsigned short*)Ap + (size_t)row * 512 + 32 * kk + 8 * quad);
        } else {
            const float* ap = (const float*)Ap + (size_t)row * 512 + 32 * kk + 8 * quad;
            float4 x0 = *(const float4*)ap;
            float4 x1 = *(const float4*)(ap + 4);
            af[0] = (short)f2bf(x0.x); af[1] = (short)f2bf(x0.y);
            af[2] = (short)f2bf(x0.z); af[3] = (short)f2bf(x0.w);
            af[4] = (short)f2bf(x1.x); af[5] = (short)f2bf(x1.y);
            af[6] = (short)f2bf(x1.z); af[7] = (short)f2bf(x1.w);
        }
        #pragma unroll
        for (int nt = 0; nt < 4; nt++) {
            short8 bf = *(const short8*)(WF +
                (((size_t)kk * 32 + (n0 >> 4) + nt) * 64 + lane) * 8);
            acc[nt] = __builtin_amdgcn_mfma_f32_16x16x32_bf16(af, bf, acc[nt], 0, 0, 0);
        }
    }

    #pragma unroll
    for (int nt = 0; nt < 4; nt++) {
        float bv = bias[n0 + 16 * nt + c];
        #pragma unroll
        for (int r = 0; r < 4; r++) {
            float v = (acc[nt][r] + bv) * oscale;
            size_t idx = (size_t)(m0 + 16 * wv + 4 * quad + r) * 512 + n0 + 16 * nt + c;
            if (OUT_BF16) ((unsigned short*)Cp)[idx] = f2bf(v);
            else          ((float*)Cp)[idx] = v;
        }
    }
}

// ---- inline-asm pinned prefetch: compiler cannot sink/remat these, and the
// "=v" outputs stay live -> true depth-1 register double-buffer.
#define GLD(dst, base, off) \
    asm volatile("global_load_dwordx4 %0, %1, off offset:" #off \
                 : "=v"(dst) : "v"(base) : "memory")
#define WAITV(n) asm volatile("s_waitcnt vmcnt(" #n ")" ::: "memory")
#define SCHEDB() __builtin_amdgcn_sched_barrier(0)

// ---- barrier-free MFMA flash attention, XCD-swizzled grid: the 4 qt-blocks
// of one (b,h) share blockIdx%8 -> same XCD -> shared L2 stream of KF/VF.
// No-max softmax (Q pre-scaled by scale*log2e); row sums via ones-MFMA.
// Pipeline: per tile 16x global_load_dwordx4 issued one tile ahead via inline
// asm; each compute gated by s_waitcnt vmcnt(16) (next tile's 16 stay in
// flight — never drain to 0 mid-loop) + sched_barrier(0) (hipcc hoists
// register-only MFMA past inline-asm waitcnt otherwise).
__global__ __launch_bounds__(256, 2) void attn_frag(const unsigned short* __restrict__ Q,
                                                    const unsigned short* __restrict__ KF,
                                                    const unsigned short* __restrict__ VF,
                                                    unsigned short* __restrict__ X) {
    __shared__ unsigned short Pw[4][16 * KSTR];

    // swizzle: raw = xcd + 8*(qt + 4*grp); bh = grp*8 + xcd -> b=grp, h=xcd
    const int raw = blockIdx.x;
    const int h  = raw & 7;            // = xcd slot
    const int qt = (raw >> 3) & 3;
    const int b  = raw >> 5;
    const int tid = threadIdx.x;
    const int wv = tid >> 6, lane = tid & 63;
    const int c = lane & 15, quad = lane >> 4;

    short8 qa[2];
    {
        const unsigned short* qsrc =
            Q + ((size_t)(b * 256 + qt * 64 + 16 * wv + c)) * 512 + h * 64;
        qa[0] = *(const short8*)(qsrc + 8 * quad);
        qa[1] = *(const short8*)(qsrc + 32 + 8 * quad);
    }
    // Drain Q loads now so the only vmem ops in flight inside the loop are our
    // inline-asm loads (keeps the vmcnt(16) counts exact).
    WAITV(0); SCHEDB();

    short8 ones;
    #pragma unroll
    for (int i = 0; i < 8; i++) ones[i] = (short)0x3F80;

    f32x4 oacc[4];
    #pragma unroll
    for (int dt = 0; dt < 4; dt++) oacc[dt] = (f32x4){0.f, 0.f, 0.f, 0.f};
    f32x4 lacc = (f32x4){0.f, 0.f, 0.f, 0.f};

    const int swc = (c >> 3) & 1;
    const int swr = (quad >> 1) & 1;

    const unsigned short* kf = KF + ((size_t)((b * 8 + h) * 32)) * 4096 + lane * 8;
    const unsigned short* vf = VF + ((size_t)((b * 8 + h) * 32)) * 4096 + lane * 8;

    short8 kc[8], vc[8], kn[8], vn[8];

    // issue one tile's 16 loads (byte offsets: f*1024; imm limit 4095 -> two bases)
#define ISSUE_TILE(kb, vb, tp) do { \
        const unsigned short* k2_ = kf + (size_t)(tp) * 4096; \
        const unsigned short* v2_ = vf + (size_t)(tp) * 4096; \
        const unsigned short* k3_ = k2_ + 2048; \
        const unsigned short* v3_ = v2_ + 2048; \
        GLD(kb[0], k2_, 0);    GLD(kb[1], k2_, 1024); \
        GLD(kb[2], k2_, 2048); GLD(kb[3], k2_, 3072); \
        GLD(kb[4], k3_, 0);    GLD(kb[5], k3_, 1024); \
        GLD(kb[6], k3_, 2048); GLD(kb[7], k3_, 3072); \
        GLD(vb[0], v2_, 0);    GLD(vb[1], v2_, 1024); \
        GLD(vb[2], v2_, 2048); GLD(vb[3], v2_, 3072); \
        GLD(vb[4], v3_, 0);    GLD(vb[5], v3_, 1024); \
        GLD(vb[6], v3_, 2048); GLD(vb[7], v3_, 3072); \
    } while (0)

    auto compute = [&](short8* kb, short8* vb) {
        f32x4 sacc[4];
        #pragma unroll
        for (int nt = 0; nt < 4; nt++) sacc[nt] = (f32x4){0.f, 0.f, 0.f, 0.f};
        #pragma unroll
        for (int nt = 0; nt < 4; nt++)
            #pragma unroll
            for (int ks = 0; ks < 2; ks++)
                sacc[nt] = __builtin_amdgcn_mfma_f32_16x16x32_bf16(
                    qa[ks], kb[nt * 2 + ks], sacc[nt], 0, 0, 0);
        #pragma unroll
        for (int nt = 0; nt < 4; nt++)
            #pragma unroll
            for (int r = 0; r < 4; r++)
                Pw[wv][(4 * quad + r) * KSTR + ((16 * nt + c) ^ (8 * swr))] =
                    f2bf(EXP2F(sacc[nt][r]));
        short8 pa0 = *(const short8*)&Pw[wv][c * KSTR + (8 * (quad ^ swc))];
        short8 pa1 = *(const short8*)&Pw[wv][c * KSTR + 32 + (8 * (quad ^ swc))];
        #pragma unroll
        for (int dt = 0; dt < 4; dt++) {
            oacc[dt] = __builtin_amdgcn_mfma_f32_16x16x32_bf16(pa0, vb[dt * 2], oacc[dt], 0, 0, 0);
            oacc[dt] = __builtin_amdgcn_mfma_f32_16x16x32_bf16(pa1, vb[dt * 2 + 1], oacc[dt], 0, 0, 0);
        }
        lacc = __builtin_amdgcn_mfma_f32_16x16x32_bf16(pa0, ones, lacc, 0, 0, 0);
        lacc = __builtin_amdgcn_mfma_f32_16x16x32_bf16(pa1, ones, lacc, 0, 0, 0);
    };

    ISSUE_TILE(kc, vc, 0);
    for (int t = 0; t < 32; t += 2) {
        ISSUE_TILE(kn, vn, t + 1);
        WAITV(16); SCHEDB();           // tile t's 16 loads done; t+1's in flight
        compute(kc, vc);
        if (t + 2 < 32) {
            ISSUE_TILE(kc, vc, t + 2);
            WAITV(16); SCHEDB();       // tile t+1 done; t+2 in flight
        } else {
            WAITV(0); SCHEDB();        // epilogue drain
        }
        compute(kn, vn);
    }

    #pragma unroll
    for (int r = 0; r < 4; r++) {
        float inv = 1.f / lacc[r];
        size_t row = (size_t)(b * 256 + qt * 64 + 16 * wv + 4 * quad + r);
        unsigned short* xp = X + row * 512 + h * 64;
        #pragma unroll
        for (int dt = 0; dt < 4; dt++)
            xp[16 * dt + c] = f2bf(oacc[dt][r] * inv);
    }
#undef ISSUE_TILE
}

// ---------------------------------------------------------------------------
extern "C" void kernel_launch(void* const* d_in, const int* in_sizes, int n_in,
                              void* d_out, int out_size, void* d_ws, size_t ws_size,
                              hipStream_t stream) {
    const float* Lmat = (const float*)d_in[0];  // [16,2048,512]
    const float* G    = (const float*)d_in[1];  // [16,256,512]
    const float* Wq   = (const float*)d_in[2];  // [512,512]
    const float* bq   = (const float*)d_in[3];  // [512]
    const float* Wo   = (const float*)d_in[4];  // [512,512]
    const float* bo   = (const float*)d_in[5];  // [512]
    float* out = (float*)d_out;                 // [16,256,512] f32

    const float SCe = 0.005524271728019903f * 1.4426950408889634f;  // scale*log2e
    dim3 gg(64, 8);

    // ws layout (bf16 elems): Qws 2M | Xws 2M | WqF 256K | WoF 256K | KF 16M | VF 16M
    unsigned short* Qws = (unsigned short*)d_ws;
    unsigned short* Xws = Qws + (size_t)2097152;
    unsigned short* WqF = Xws + (size_t)2097152;
    unsigned short* WoF = WqF + (size_t)262144;
    unsigned short* KF  = WoF + (size_t)262144;
    unsigned short* VF  = KF  + (size_t)16777216;

    conv_W<<<dim3(128, 2), 256, 0, stream>>>(Wq, Wo, WqF, WoF);
    conv_L<<<4096, 256, 0, stream>>>(Lmat, KF, VF);
    gemm_direct<false, true><<<gg, 256, 0, stream>>>(G, WqF, bq, Qws, SCe);
    attn_frag<<<512, 256, 0, stream>>>(Qws, KF, VF, Xws);
    gemm_direct<true, false><<<gg, 256, 0, stream>>>(Xws, WoF, bo, out, 1.0f);
}